// Round 14
// baseline (28.349 us; speedup 1.0000x reference)
//
#include <hip/hip_runtime.h>

typedef __attribute__((ext_vector_type(4))) float f32x4;
typedef __attribute__((ext_vector_type(8))) _Float16 f16x8;
typedef __attribute__((ext_vector_type(4))) _Float16 f16x4;

#define D_ 64
#define K_ 512

// 2-limb f16: a = hi + lo (22 mantissa bits), limbs K-concatenated (128 k's).
// Frag image element (tile, kb, ko, r, s) at halves-offset tile*2048 + kb*512 +
// ko*128 + r*8 + s = limb of dim kb*32 + ko*4 + 16*(s>>2) + (s&3)  (hi for
// kb<2, lo for kb>=2). IDENTICAL convention for codebook image (prep) and
// query staging (main) => within-K-block permutation cancels in A.B.
// Queries NEGATED; acc seeded with 0.5||e||^2 (ws esq) via MFMA C-operand:
// score = 0.5||e||^2 - c.e (lo.lo dropped, ~1.5e-5; absmax 0.0 rounds 5-13).

// ===================== prep: codebook -> ws frag image + 0.5||e||^2 ==============
__global__ __launch_bounds__(128, 1)
void vq_prep(const float* __restrict__ cb, _Float16* __restrict__ bf,
             float* __restrict__ esq) {
  const int tid = blockIdx.x * 128 + threadIdx.x;   // grid 8 x 128 = 1024
  const int e = tid >> 1, half = tid & 1;           // 2 threads per entry
  const float* src = cb + e * D_ + half * 32;
  _Float16 hi[32], lo[32];
  float es = 0.f;
#pragma unroll
  for (int g = 0; g < 8; ++g) {
    f32x4 v = *(const f32x4*)(src + 4 * g);
#pragma unroll
    for (int j = 0; j < 4; ++j) {
      float a = v[j];
      es += a * a;
      _Float16 h = (_Float16)a;
      hi[4 * g + j] = h;
      lo[4 * g + j] = (_Float16)(a - (float)h);
    }
  }
  es += __shfl_xor(es, 1, 64);                      // combine the two halves
  if (half == 0) esq[e] = 0.5f * es;
  const int tile = e >> 4, r = e & 15;
  _Float16* dst = bf + tile * 2048 + r * 8;
#pragma unroll
  for (int ko = 0; ko < 4; ++ko) {
    f16x8 wh, wl;
#pragma unroll
    for (int s = 0; s < 8; ++s) {
      int loc = ko * 4 + (s >> 2) * 16 + (s & 3);   // dim within this 32-block
      wh[s] = hi[loc];
      wl[s] = lo[loc];
    }
    *(f16x8*)(dst + half * 512 + ko * 128) = wh;        // kb = half   (hi limb)
    *(f16x8*)(dst + (2 + half) * 512 + ko * 128) = wl;  // kb = half+2 (lo limb)
  }
}

// ====== main: grid 512 x 1024 thr (16 waves), Q=128/block, 2 blocks/CU ==========
// Co-resident blocks phase-offset: one block's barrier-free sweep hides the
// other's staging / combine / gather / write (the measured ~16us fixed term).
__global__ __launch_bounds__(1024, 2)
void vq_main(const float* __restrict__ codes, const float* __restrict__ codebook,
             const _Float16* __restrict__ bf, const float* __restrict__ esq,
             float* __restrict__ out) {
  __shared__ _Float16 Af[128 * 128];     // 32 KB query frags (8 q-tiles)
  __shared__ float smin[16][128];        // 8 KB
  __shared__ int   simin[16][128];       // 8 KB
  __shared__ int   best[128];            // 0.5 KB

  const int t = threadIdx.x;
  const int w = t >> 6, l = t & 63, lh = l >> 4, ll = l & 15;
  const long long qb = (long long)blockIdx.x * 128;

  // ---- issue query loads first: thread -> query aq, dims dpart*8..+7 ----
  const int aq = t >> 3, dpart = t & 7;
  const float* asrc = codes + (qb + aq) * D_ + dpart * 8;
  f32x4 av0 = *(const f32x4*)asrc;
  f32x4 av1 = *(const f32x4*)(asrc + 4);

  // ---- ef frags + esq from ws image (L2-hot; no conversion, no shfl chain) ----
  f16x8 ef[2][4];                        // wave owns tiles 2w, 2w+1
  f32x4 esqr[2];
#pragma unroll
  for (int i = 0; i < 2; ++i) {
#pragma unroll
    for (int kb = 0; kb < 4; ++kb)
      ef[i][kb] = *(const f16x8*)(bf + (w * 2 + i) * 2048 + kb * 512 + l * 8);
    esqr[i] = *(const f32x4*)(esq + (w * 2 + i) * 16 + lh * 4);
  }

  // ---- stage own queries: negated 2-limb frags, 4 x ds_write_b64 ----
  {
    const int kb = dpart >> 2;                  // dims dpart*8 -> kb, p
    const int p = dpart & 3;
    const int j = p >> 1, lh0 = (p & 1) * 2;    // dims: lh0*4+16j (av0), (lh0+1)*4+16j (av1)
    _Float16* base = Af + (aq >> 4) * 2048 + kb * 512 + (aq & 15) * 8 + j * 4;
#pragma unroll
    for (int m = 0; m < 2; ++m) {
      f32x4 vv = m ? av1 : av0;
      f16x4 wh, wl;
#pragma unroll
      for (int si = 0; si < 4; ++si) {
        float na = -vv[si];                     // negate query
        _Float16 h = (_Float16)na;
        wh[si] = h;
        wl[si] = (_Float16)(na - (float)h);
      }
      *(f16x4*)(base + (lh0 + m) * 128) = wh;          // hi limb: kb
      *(f16x4*)(base + 1024 + (lh0 + m) * 128) = wl;   // lo limb: kb+2
    }
  }
  __syncthreads();                              // barrier #1: Af ready

  // ---- main loop: 8 q-tiles, barrier-free ----
#pragma unroll 2
  for (int qt = 0; qt < 8; ++qt) {
    f16x8 qf[4];
#pragma unroll
    for (int kb = 0; kb < 4; ++kb)
      qf[kb] = *(const f16x8*)(&Af[qt * 2048 + kb * 512 + l * 8]);

    // two independent MFMA chains (ILP)
    f32x4 a0 = esqr[0], a1 = esqr[1];
    a0 = __builtin_amdgcn_mfma_f32_16x16x32_f16(ef[0][0], qf[0], a0, 0, 0, 0);
    a1 = __builtin_amdgcn_mfma_f32_16x16x32_f16(ef[1][0], qf[0], a1, 0, 0, 0);
    a0 = __builtin_amdgcn_mfma_f32_16x16x32_f16(ef[0][1], qf[1], a0, 0, 0, 0);
    a1 = __builtin_amdgcn_mfma_f32_16x16x32_f16(ef[1][1], qf[1], a1, 0, 0, 0);
    a0 = __builtin_amdgcn_mfma_f32_16x16x32_f16(ef[0][2], qf[0], a0, 0, 0, 0);
    a1 = __builtin_amdgcn_mfma_f32_16x16x32_f16(ef[1][2], qf[0], a1, 0, 0, 0);
    a0 = __builtin_amdgcn_mfma_f32_16x16x32_f16(ef[0][3], qf[1], a0, 0, 0, 0);
    a1 = __builtin_amdgcn_mfma_f32_16x16x32_f16(ef[1][3], qf[1], a1, 0, 0, 0);
    a0 = __builtin_amdgcn_mfma_f32_16x16x32_f16(ef[0][0], qf[2], a0, 0, 0, 0);
    a1 = __builtin_amdgcn_mfma_f32_16x16x32_f16(ef[1][0], qf[2], a1, 0, 0, 0);
    a0 = __builtin_amdgcn_mfma_f32_16x16x32_f16(ef[0][1], qf[3], a0, 0, 0, 0);
    a1 = __builtin_amdgcn_mfma_f32_16x16x32_f16(ef[1][1], qf[3], a1, 0, 0, 0);

    float mv0 = a0[0]; int mi0 = (w * 2) * 16 + lh * 4;
    float mv1 = a1[0]; int mi1 = (w * 2 + 1) * 16 + lh * 4;
#pragma unroll
    for (int r = 1; r < 4; ++r) {
      if (a0[r] < mv0) { mv0 = a0[r]; mi0 = (w * 2) * 16 + lh * 4 + r; }
      if (a1[r] < mv1) { mv1 = a1[r]; mi1 = (w * 2 + 1) * 16 + lh * 4 + r; }
    }
    float mv = mv0; int mi = mi0;
    if (mv1 < mv0) { mv = mv1; mi = mi1; }      // i=1 indices strictly larger

    // reduce over the 4 lh groups (same query col, different entries)
#pragma unroll
    for (int off = 16; off <= 32; off <<= 1) {
      float ov = __shfl_xor(mv, off, 64);
      int oi = __shfl_xor(mi, off, 64);
      if (ov < mv || (ov == mv && oi < mi)) { mv = ov; mi = oi; }
    }
    if (l < 16) {
      smin[w][qt * 16 + ll] = mv;
      simin[w][qt * 16 + ll] = mi;
    }
  }
  __syncthreads();                              // barrier #2: all smin written

  // ---- combine 16 waves (disjoint ascending entry ranges; tie -> lower index) ----
  if (t < 128) {
    float bv = smin[0][t]; int bi = simin[0][t];
#pragma unroll
    for (int ww = 1; ww < 16; ++ww) {
      float v = smin[ww][t]; int ii = simin[ww][t];
      if (v < bv || (v == bv && ii < bi)) { bv = v; bi = ii; }
    }
    best[t] = bi;
  }
  __syncthreads();

  // ---- gather: exact fp32 rows (L2-hot codebook), non-temporal out stores ----
#pragma unroll
  for (int i2 = 0; i2 < 2; ++i2) {
    const int f = t + 1024 * i2;                // 2048 f32x4 per block
    const int q = f >> 4, g = f & 15;
    const int e = best[q];
    f32x4 v = *(const f32x4*)(codebook + e * D_ + g * 4);
    __builtin_nontemporal_store(v, (f32x4*)(out + (qb + q) * D_ + g * 4));
  }
}

extern "C" void kernel_launch(void* const* d_in, const int* in_sizes, int n_in,
                              void* d_out, int out_size, void* d_ws, size_t ws_size,
                              hipStream_t stream) {
  const float* codes = (const float*)d_in[0];
  const float* codebook = (const float*)d_in[1];
  float* out = (float*)d_out;
  _Float16* bf = (_Float16*)d_ws;                        // 128 KB frag image
  float* esq = (float*)((char*)d_ws + 131072);           // 2 KB norms
  vq_prep<<<8, 128, 0, stream>>>(codebook, bf, esq);
  const int Q = in_sizes[0] / D_;        // 65536
  vq_main<<<Q / 128, 1024, 0, stream>>>(codes, codebook, bf, esq, out);
}

// Round 15
// 24.712 us; speedup vs baseline: 1.1472x; 1.1472x over previous
//
#include <hip/hip_runtime.h>

typedef __attribute__((ext_vector_type(4))) float f32x4;
typedef __attribute__((ext_vector_type(16))) float f32x16;
typedef __attribute__((ext_vector_type(8))) _Float16 f16x8;

#define D_ 64
#define K_ 512

// 2-limb f16 (a = hi + lo, 22 mantissa bits) on mfma_f32_32x32x16_f16.
// K-space = 128 limbs in 8 k-blocks of 16: kb 0-3 = hi(dims 16kb..16kb+15),
// kb 4-7 = lo. Within a k-block, operand slot (lane>>5, s) holds dim-pos
// (lane>>5)*8 + s — IDENTICAL builder for entries (A) and queries (B), so any
// mismatch vs the true HW k-mapping cancels in A.B. Queries NEGATED; acc
// seeded with 0.5||e||^2 via the C-operand: score = 0.5||e||^2 - c.e
// (lo.lo dropped, ~1.5e-5; absmax 0.0 rounds 5-14).
// C/D (HW-verified m74/m101): col = lane&31 = query, row = (reg&3) + 8*(reg>>2)
// + 4*(lane>>5) = entry-within-tile -> argmin fold in-lane, ONE shfl_xor(32).
//
// Structure: grid 256 x 512 thr (8 waves, 2/SIMD), Q=256/block. Wave owns 64
// entries (two 32-tiles, 2 independent 12-MFMA chains). Single-phase staging,
// barrier-free qt sweep (8 q-tiles of 32). vs r8-13: HALF the MFMA issue slots,
// +15% MFMA rate, 1 shfl per qt instead of 2 (attacks the 41%-util issue gap).
__global__ __launch_bounds__(512, 2)
void vq_fused(const float* __restrict__ codes,
              const float* __restrict__ codebook,
              float* __restrict__ out) {
  __shared__ _Float16 Af[256 * 128];     // 64 KB query frags
  __shared__ float esq_s[K_];            // 2 KB
  __shared__ float smin[8][256];         // 8 KB
  __shared__ int   simin[8][256];        // 8 KB
  __shared__ int   best[256];            // 1 KB

  const int t = threadIdx.x;
  const int w = t >> 6, l = t & 63;
  const int l32 = l & 31, lhi = l >> 5;
  const long long qb = (long long)blockIdx.x * 256;

  // ---- issue query loads first: thread -> query ql, dims dhalf..dhalf+31 ----
  const int ql = t >> 1, dhalf = (t & 1) * 32;
  const float* asrc = codes + (qb + ql) * D_ + dhalf;
  f32x4 av[8];
#pragma unroll
  for (int g = 0; g < 8; ++g) av[g] = *(const f32x4*)(asrc + 4 * g);

  // ---- build ef frags + 0.5||e||^2 (wave owns entries 64w..64w+63) ----
  // lane covers entry e = 64w + 32i + l32, k-positions lhi*8+s of each k-block
  f16x8 ef[2][8];                        // [tile][kb] kb0-3 hi, kb4-7 lo
#pragma unroll
  for (int i = 0; i < 2; ++i) {
    const int e = w * 64 + i * 32 + l32;
    float es = 0.f;
#pragma unroll
    for (int kb = 0; kb < 4; ++kb) {
      const float* src = codebook + e * D_ + kb * 16 + lhi * 8;
      f32x4 v0 = *(const f32x4*)src;
      f32x4 v1 = *(const f32x4*)(src + 4);
#pragma unroll
      for (int s = 0; s < 8; ++s) {
        float a = (s < 4) ? v0[s & 3] : v1[s & 3];
        es += a * a;
        _Float16 h = (_Float16)a;
        ef[i][kb][s] = h;
        ef[i][4 + kb][s] = (_Float16)(a - (float)h);
      }
    }
    es += __shfl_xor(es, 32, 64);        // lane pair covers all 64 dims
    if (lhi == 0) esq_s[e] = 0.5f * es;
  }

  // ---- stage queries: negated 2-limb frags, 8 x ds_write_b128 ----
  {
    const int kbs = (t & 1) * 2;         // thread's two k-blocks
    const int qtile = ql >> 5, qr = ql & 31;
#pragma unroll
    for (int kk = 0; kk < 2; ++kk)
#pragma unroll
      for (int ph = 0; ph < 2; ++ph) {
        f16x8 wh, wl;
#pragma unroll
        for (int s = 0; s < 8; ++s) {
          float na = -av[kk * 4 + ph * 2 + (s >> 2)][s & 3];
          _Float16 h = (_Float16)na;
          wh[s] = h;
          wl[s] = (_Float16)(na - (float)h);
        }
        _Float16* dst = Af + qtile * 4096 + (kbs + kk) * 512 + ph * 256 + qr * 8;
        *(f16x8*)dst = wh;               // hi k-block
        *(f16x8*)(dst + 2048) = wl;      // lo k-block (kb+4)
      }
  }
  __syncthreads();                       // barrier #1: Af + esq_s ready

  // per-lane 0.5||e||^2 for C/D rows: row(reg) = (reg&3) + 8*(reg>>2) + 4*lhi
  f32x4 esqr[2][4];
#pragma unroll
  for (int i = 0; i < 2; ++i)
#pragma unroll
    for (int g = 0; g < 4; ++g)
      esqr[i][g] = *(const f32x4*)(esq_s + w * 64 + i * 32 + 8 * g + 4 * lhi);

  // ---- main loop: 8 q-tiles of 32 queries, barrier-free ----
  for (int qt = 0; qt < 8; ++qt) {
    f16x8 qf[8];
#pragma unroll
    for (int kb = 0; kb < 8; ++kb)
      qf[kb] = *(const f16x8*)(&Af[qt * 4096 + kb * 512 + lhi * 256 + l32 * 8]);

    f32x16 a0, a1;
#pragma unroll
    for (int g = 0; g < 4; ++g)
#pragma unroll
      for (int r = 0; r < 4; ++r) {
        a0[4 * g + r] = esqr[0][g][r];   // C seed: 0.5||e||^2
        a1[4 * g + r] = esqr[1][g][r];
      }

    // two independent 12-MFMA chains (tile0 / tile1), interleaved
#pragma unroll
    for (int kb = 0; kb < 4; ++kb) {     // hh: eh . (-ch)
      a0 = __builtin_amdgcn_mfma_f32_32x32x16_f16(ef[0][kb], qf[kb], a0, 0, 0, 0);
      a1 = __builtin_amdgcn_mfma_f32_32x32x16_f16(ef[1][kb], qf[kb], a1, 0, 0, 0);
    }
#pragma unroll
    for (int kb = 0; kb < 4; ++kb) {     // eh . (-cl)
      a0 = __builtin_amdgcn_mfma_f32_32x32x16_f16(ef[0][kb], qf[4 + kb], a0, 0, 0, 0);
      a1 = __builtin_amdgcn_mfma_f32_32x32x16_f16(ef[1][kb], qf[4 + kb], a1, 0, 0, 0);
    }
#pragma unroll
    for (int kb = 0; kb < 4; ++kb) {     // el . (-ch)
      a0 = __builtin_amdgcn_mfma_f32_32x32x16_f16(ef[0][4 + kb], qf[kb], a0, 0, 0, 0);
      a1 = __builtin_amdgcn_mfma_f32_32x32x16_f16(ef[1][4 + kb], qf[kb], a1, 0, 0, 0);
    }

    // per-lane argmin over 32 rows (ascending reg = ascending entry)
    float mv = 3.4e38f; int mi = 0;
#pragma unroll
    for (int g = 0; g < 4; ++g)
#pragma unroll
      for (int r = 0; r < 4; ++r) {
        const int e0 = w * 64 + 8 * g + 4 * lhi + r;          // tile 0
        if (a0[4 * g + r] < mv) { mv = a0[4 * g + r]; mi = e0; }
      }
#pragma unroll
    for (int g = 0; g < 4; ++g)
#pragma unroll
      for (int r = 0; r < 4; ++r) {
        const int e1 = w * 64 + 32 + 8 * g + 4 * lhi + r;     // tile 1 (larger idx)
        if (a1[4 * g + r] < mv) { mv = a1[4 * g + r]; mi = e1; }
      }
    // combine the two lane-halves (same query col l32, disjoint rows)
    {
      float ov = __shfl_xor(mv, 32, 64);
      int oi = __shfl_xor(mi, 32, 64);
      if (ov < mv || (ov == mv && oi < mi)) { mv = ov; mi = oi; }
    }
    if (lhi == 0) {
      smin[w][qt * 32 + l32] = mv;
      simin[w][qt * 32 + l32] = mi;
    }
  }
  __syncthreads();                       // barrier #2: all smin written

  // ---- combine 8 waves (disjoint ascending entry ranges; tie -> lower index) ----
  if (t < 256) {
    float bv = smin[0][t]; int bi = simin[0][t];
#pragma unroll
    for (int ww = 1; ww < 8; ++ww) {
      float v = smin[ww][t]; int ii = simin[ww][t];
      if (v < bv || (v == bv && ii < bi)) { bv = v; bi = ii; }
    }
    best[t] = bi;
  }
  __syncthreads();

  // ---- gather: exact fp32 rows (L2-hot codebook), non-temporal out stores ----
#pragma unroll
  for (int i2 = 0; i2 < 8; ++i2) {
    const int f = t + 512 * i2;          // 4096 f32x4 per block
    const int q = f >> 4, g = f & 15;
    const int e = best[q];
    f32x4 v = *(const f32x4*)(codebook + e * D_ + g * 4);
    __builtin_nontemporal_store(v, (f32x4*)(out + (qb + q) * D_ + g * 4));
  }
}

extern "C" void kernel_launch(void* const* d_in, const int* in_sizes, int n_in,
                              void* d_out, int out_size, void* d_ws, size_t ws_size,
                              hipStream_t stream) {
  const float* codes = (const float*)d_in[0];
  const float* codebook = (const float*)d_in[1];
  float* out = (float*)d_out;
  const int Q = in_sizes[0] / D_;        // 65536
  const int grid = Q / 256;              // 256
  vq_fused<<<grid, 512, 0, stream>>>(codes, codebook, out);
}